// Round 1
// baseline (341.932 us; speedup 1.0000x reference)
//
#include <hip/hip_runtime.h>
#include <hip/hip_bf16.h>
#include <math.h>

#define LHIST 50

typedef __attribute__((ext_vector_type(8))) short bf16x8;
typedef __attribute__((ext_vector_type(4))) float f32x4;

__device__ __forceinline__ unsigned short f2bf(float f) {
    union { float f; unsigned u; } v; v.f = f;
    unsigned r = v.u + 0x7fff + ((v.u >> 16) & 1);   // RNE
    return (unsigned short)(r >> 16);
}
__device__ __forceinline__ float bf2f(unsigned short h) {
    union { unsigned u; float f; } v; v.u = ((unsigned)h) << 16;
    return v.f;
}
__device__ __forceinline__ unsigned pk2(float lo, float hi) {   // v_cvt_pk_bf16_f32
    __hip_bfloat162 h = __float22bfloat162_rn(make_float2(lo, hi));
    return *(unsigned*)&h;
}

// ws float offsets:
//  W13fb  frag bf16 [nt5][ks2][lane][8]   @ 0         (2560 f)   (W1+W3)
//  Bmfb   frag bf16 [nt5][ks2][lane][8]   @ 5120      (2560 f)   (W2-W3)
//  W4fb   frag bf16 [nt5][ks2][lane][8]   @ 7680      (2560 f)   (W4)
//  W1f    frag bf16 [nt16][ks5][lane][8]  @ 10240     (20480 f)
//  W2f    frag bf16 [nt8][ks8][lane][8]   @ 30720     (16384 f)
//  itemb  bf16 [NI*32]                    @ 47104     (NI*16 f)
//  catb   bf16 [NC*32]                    @ 47104+NI*16
//  combined [B][160] fp32                 after catb

__global__ void prep_kernel(const float* __restrict__ aw1,
                            const float* __restrict__ mw1,
                            const float* __restrict__ mw2,
                            const float* __restrict__ item_table,
                            const float* __restrict__ cat_table,
                            int itemN, int catN,
                            unsigned short* __restrict__ W13fb,
                            unsigned short* __restrict__ Bmfb,
                            unsigned short* __restrict__ W4fb,
                            unsigned short* __restrict__ W1f,
                            unsigned short* __restrict__ W2f,
                            unsigned short* __restrict__ itemb,
                            unsigned short* __restrict__ catb) {
    int i = blockIdx.x * 256 + threadIdx.x;
    int i8 = i * 8;
    if (i8 + 7 < itemN) {
        float4 a = *(const float4*)&item_table[i8];
        float4 b = *(const float4*)&item_table[i8 + 4];
        uint4 r;
        r.x = pk2(a.x, a.y); r.y = pk2(a.z, a.w);
        r.z = pk2(b.x, b.y); r.w = pk2(b.z, b.w);
        *(uint4*)&itemb[i8] = r;
    }
    if (i8 + 7 < catN) {
        float4 a = *(const float4*)&cat_table[i8];
        float4 b = *(const float4*)&cat_table[i8 + 4];
        uint4 r;
        r.x = pk2(a.x, a.y); r.y = pk2(a.z, a.w);
        r.z = pk2(b.x, b.y); r.w = pk2(b.z, b.w);
        *(uint4*)&catb[i8] = r;
    }
    if (i < 5120) {
        int kk = i / 80, n = i - kk * 80;
        int nt = n >> 4, colw = n & 15, ks = kk >> 5, r = kk & 31, qd = r >> 3, off = r & 7;
        int d = ((nt * 2 + ks) * 64 + qd * 16 + colw) * 8 + off;
        Bmfb[d]  = f2bf(aw1[(64 + kk) * 80 + n] - aw1[(128 + kk) * 80 + n]);   // W2-W3
        W4fb[d]  = f2bf(aw1[(192 + kk) * 80 + n]);                              // W4
        W13fb[d] = f2bf(aw1[kk * 80 + n] + aw1[(128 + kk) * 80 + n]);           // W1+W3
    }
    if (i < 40960) {
        int kk = i >> 8, n = i & 255;
        int nt = n >> 4, colw = n & 15, ks = kk >> 5, r = kk & 31, qd = r >> 3, off = r & 7;
        W1f[((nt * 5 + ks) * 64 + qd * 16 + colw) * 8 + off] = f2bf(mw1[i]);
    }
    if (i < 32768) {
        int kk = i >> 7, n = i & 127;
        int nt = n >> 4, colw = n & 15, ks = kk >> 5, r = kk & 31, qd = r >> 3, off = r & 7;
        W2f[((nt * 8 + ks) * 64 + qd * 16 + colw) * 8 + off] = f2bf(mw2[i]);
    }
}

// ---------- attention: 1 wave = 1 batch, barrier-free ----------
// score[l][j] = relu( q.(W1+W3)[j] + h[l].(W2-W3)[:,j] + (h[l]*q).W4[:,j] + ab1[j] ) . aw2
// Weight frags are batch-invariant (L1-resident); per-batch work is hq = h*q only.
__global__ void __launch_bounds__(256, 4) attn_kernel(
    const int* __restrict__ cid, const int* __restrict__ cg,
    const int* __restrict__ cc,  const int* __restrict__ hg,
    const int* __restrict__ hc,
    const float* __restrict__ user_table, const float* __restrict__ item_table,
    const float* __restrict__ cat_table,
    const float* __restrict__ ab1, const float* __restrict__ aw2,
    const unsigned short* __restrict__ W13fb, const unsigned short* __restrict__ Bmfb,
    const unsigned short* __restrict__ W4fb,
    const unsigned short* __restrict__ itemb, const unsigned short* __restrict__ catb,
    float* __restrict__ combined)
{
    __shared__ float red[4][1056];   // per-wave private att transpose scratch (16.9 KB)

    const int t = threadIdx.x;
    const int wv = t >> 6;
    const int lane = t & 63;
    const int quad = lane >> 4;
    const int col = lane & 15;
    const int b = blockIdx.x * 4 + wv;

    const int cgb = cg[b], ccb = cc[b];

    // ---- indices + gathers (l = mi*16 + col) ----
    int il[4], ic[4];
    bool bad[4];
    #pragma unroll
    for (int mi = 0; mi < 4; ++mi) {
        int l = mi * 16 + col;
        int lc = (l < LHIST) ? l : 0;
        il[mi] = hg[b * LHIST + lc];
        ic[mi] = hc[b * LHIST + lc];
        bad[mi] = (l >= LHIST) || (il[mi] == 0);
    }
    uint4 vi[4], vc[4];
    #pragma unroll
    for (int mi = 0; mi < 4; ++mi) {
        vi[mi] = *(const uint4*)&itemb[(size_t)il[mi] * 32 + quad * 8];
        vc[mi] = *(const uint4*)&catb[(size_t)ic[mi] * 32 + quad * 8];
    }
    // q fp32 chunks for this lane's d-range (d = quad*8 .. +7)
    const float4 qia = *(const float4*)&item_table[(size_t)cgb * 32 + quad * 8];
    const float4 qib = *(const float4*)&item_table[(size_t)cgb * 32 + quad * 8 + 4];
    const float4 qca = *(const float4*)&cat_table[(size_t)ccb * 32 + quad * 8];
    const float4 qcb = *(const float4*)&cat_table[(size_t)ccb * 32 + quad * 8 + 4];

    // bf16 broadcast-q B-frags (col-independent): B[k=quad*8+off][*] = q[k]
    bf16x8 qbi, qbc;
    {
        uint4 u, v;
        u.x = pk2(qia.x, qia.y); u.y = pk2(qia.z, qia.w);
        u.z = pk2(qib.x, qib.y); u.w = pk2(qib.z, qib.w);
        v.x = pk2(qca.x, qca.y); v.y = pk2(qca.z, qca.w);
        v.z = pk2(qcb.x, qcb.y); v.w = pk2(qcb.z, qcb.w);
        qbi = *(bf16x8*)&u;
        qbc = *(bf16x8*)&v;
    }

    // ---- hq = h * q frags (fp32 q, bf16 repack) ----
    bf16x8 hqi[4], hqc[4];
    #pragma unroll
    for (int mi = 0; mi < 4; ++mi) {
        union { uint4 u; unsigned short s[8]; } h;
        h.u = vi[mi];
        uint4 r;
        r.x = pk2(bf2f(h.s[0]) * qia.x, bf2f(h.s[1]) * qia.y);
        r.y = pk2(bf2f(h.s[2]) * qia.z, bf2f(h.s[3]) * qia.w);
        r.z = pk2(bf2f(h.s[4]) * qib.x, bf2f(h.s[5]) * qib.y);
        r.w = pk2(bf2f(h.s[6]) * qib.z, bf2f(h.s[7]) * qib.w);
        hqi[mi] = *(bf16x8*)&r;
        h.u = vc[mi];
        uint4 rc;
        rc.x = pk2(bf2f(h.s[0]) * qca.x, bf2f(h.s[1]) * qca.y);
        rc.y = pk2(bf2f(h.s[2]) * qca.z, bf2f(h.s[3]) * qca.w);
        rc.z = pk2(bf2f(h.s[4]) * qcb.x, bf2f(h.s[5]) * qcb.y);
        rc.w = pk2(bf2f(h.s[6]) * qcb.z, bf2f(h.s[7]) * qcb.w);
        hqc[mi] = *(bf16x8*)&rc;
    }

    // ---- bias accumulators per j-tile via MFMA (D row=quad*4+i matches score acc) ----
    f32x4 accb[5];
    #pragma unroll
    for (int jt = 0; jt < 5; ++jt) {
        bf16x8 w0 = *(const bf16x8*)&W13fb[((jt * 2 + 0) * 64 + lane) * 8];
        bf16x8 w1 = *(const bf16x8*)&W13fb[((jt * 2 + 1) * 64 + lane) * 8];
        f32x4 a = (f32x4){0.f, 0.f, 0.f, 0.f};
        a = __builtin_amdgcn_mfma_f32_16x16x32_bf16(w0, qbi, a, 0, 0, 0);
        a = __builtin_amdgcn_mfma_f32_16x16x32_bf16(w1, qbc, a, 0, 0, 0);
        float4 b4 = *(const float4*)&ab1[jt * 16 + quad * 4];
        a[0] += b4.x; a[1] += b4.y; a[2] += b4.z; a[3] += b4.w;
        accb[jt] = a;
    }

    // ---- score MFMAs: D[j][l] = bias + h.(W2-W3) + hq.W4 ----
    float px[4] = {0.f, 0.f, 0.f, 0.f};
    #pragma unroll
    for (int jt = 0; jt < 5; ++jt) {
        bf16x8 a23_0 = *(const bf16x8*)&Bmfb[((jt * 2 + 0) * 64 + lane) * 8];
        bf16x8 a23_1 = *(const bf16x8*)&Bmfb[((jt * 2 + 1) * 64 + lane) * 8];
        bf16x8 a4_0  = *(const bf16x8*)&W4fb[((jt * 2 + 0) * 64 + lane) * 8];
        bf16x8 a4_1  = *(const bf16x8*)&W4fb[((jt * 2 + 1) * 64 + lane) * 8];
        float4 a2 = *(const float4*)&aw2[jt * 16 + quad * 4];
        #pragma unroll
        for (int mi = 0; mi < 4; ++mi) {
            f32x4 acc = accb[jt];
            acc = __builtin_amdgcn_mfma_f32_16x16x32_bf16(a23_0, *(bf16x8*)&vi[mi], acc, 0, 0, 0);
            acc = __builtin_amdgcn_mfma_f32_16x16x32_bf16(a23_1, *(bf16x8*)&vc[mi], acc, 0, 0, 0);
            acc = __builtin_amdgcn_mfma_f32_16x16x32_bf16(a4_0, hqi[mi], acc, 0, 0, 0);
            acc = __builtin_amdgcn_mfma_f32_16x16x32_bf16(a4_1, hqc[mi], acc, 0, 0, 0);
            px[mi] += fmaxf(acc[0], 0.f) * a2.x
                    + fmaxf(acc[1], 0.f) * a2.y
                    + fmaxf(acc[2], 0.f) * a2.z
                    + fmaxf(acc[3], 0.f) * a2.w;
        }
    }

    // ---- reduce over quads (j coverage): all lanes end with full score[l=mi*16+col] ----
    #pragma unroll
    for (int mi = 0; mi < 4; ++mi) {
        px[mi] += __shfl_xor(px[mi], 16);
        px[mi] += __shfl_xor(px[mi], 32);
    }

    // ---- wave-local softmax over l ----
    float sc[4];
    #pragma unroll
    for (int mi = 0; mi < 4; ++mi) sc[mi] = bad[mi] ? -1e9f : px[mi];
    float m = fmaxf(fmaxf(sc[0], sc[1]), fmaxf(sc[2], sc[3]));
    #pragma unroll
    for (int off = 8; off >= 1; off >>= 1) m = fmaxf(m, __shfl_xor(m, off));
    float e[4];
    float ssum = 0.f;
    #pragma unroll
    for (int mi = 0; mi < 4; ++mi) {
        int l = mi * 16 + col;
        e[mi] = (l < LHIST) ? __expf(sc[mi] - m) : 0.f;
        ssum += e[mi];
    }
    #pragma unroll
    for (int off = 8; off >= 1; off >>= 1) ssum += __shfl_xor(ssum, off);
    float inv = 1.f / ssum;

    // ---- att partials: this lane's l's weighted into d = quad*8+j ----
    float ati[8], atc[8];
    #pragma unroll
    for (int j = 0; j < 8; ++j) { ati[j] = 0.f; atc[j] = 0.f; }
    #pragma unroll
    for (int mi = 0; mi < 4; ++mi) {
        float w = e[mi] * inv;
        union { uint4 u; unsigned short s[8]; } hi_, hc_;
        hi_.u = vi[mi]; hc_.u = vc[mi];
        #pragma unroll
        for (int j = 0; j < 8; ++j) {
            ati[j] += w * bf2f(hi_.s[j]);
            atc[j] += w * bf2f(hc_.s[j]);
        }
    }

    // ---- wave-private LDS transpose reduce over the 16 col-lanes (no barrier) ----
    float* myrow = &red[wv][col * 66];
    #pragma unroll
    for (int j2 = 0; j2 < 4; ++j2) {
        *(float2*)&myrow[quad * 8 + 2 * j2]      = make_float2(ati[2 * j2], ati[2 * j2 + 1]);
        *(float2*)&myrow[33 + quad * 8 + 2 * j2] = make_float2(atc[2 * j2], atc[2 * j2 + 1]);
    }
    int colIdx = (lane < 32) ? lane : 33 + (lane - 32);
    float s = 0.f;
    #pragma unroll
    for (int c = 0; c < 16; ++c) s += red[wv][c * 66 + colIdx];

    // ---- write combined [user | cand_item | cand_cat | att] ----
    float* crow = combined + (size_t)b * 160;
    const int cidb = cid[b];
    crow[lane] = (lane < 32) ? user_table[(size_t)cidb * 32 + lane]
                             : item_table[(size_t)cgb * 32 + (lane - 32)];
    if (lane < 32) crow[64 + lane] = cat_table[(size_t)ccb * 32 + lane];
    crow[96 + lane] = s;
}

// ---------- MLP: MFMA, 32 batch rows per 256-thread block (unchanged) ----------
__global__ void __launch_bounds__(256, 4) mlp_kernel(
    const float* __restrict__ combined,
    const unsigned short* __restrict__ W1f, const unsigned short* __restrict__ W2f,
    const float* __restrict__ mb1, const float* __restrict__ mb2,
    const float* __restrict__ mw3, const float* __restrict__ mb3,
    float* __restrict__ out)
{
    __shared__ __align__(16) unsigned short shA1[5120];   // [mt2][ks5][lane][8]
    __shared__ __align__(16) unsigned short shA2[8192];   // [mt2][ks8][lane][8]
    __shared__ float sh_part[4][32];

    const int t = threadIdx.x;
    const int b0 = blockIdx.x * 32;
    const int wv = t >> 6;
    const int lane = t & 63;
    const int quad = lane >> 4;
    const int col = lane & 15;

    for (int i = t; i < 1280; i += 256) {
        int m = i / 40;
        int s = i - m * 40;
        int k0 = s * 4;
        float4 v = *(const float4*)&combined[(size_t)(b0 + m) * 160 + k0];
        int mt = m >> 4, colm = m & 15;
        int ks = k0 >> 5, qd = (k0 >> 3) & 3, off = k0 & 7;
        ushort4 r; r.x = f2bf(v.x); r.y = f2bf(v.y); r.z = f2bf(v.z); r.w = f2bf(v.w);
        *(ushort4*)&shA1[((mt * 5 + ks) * 64 + qd * 16 + colm) * 8 + off] = r;
    }
    __syncthreads();

    f32x4 acc1[2][4];
    #pragma unroll
    for (int mt = 0; mt < 2; ++mt)
        #pragma unroll
        for (int j = 0; j < 4; ++j) acc1[mt][j] = (f32x4){0.f, 0.f, 0.f, 0.f};
    #pragma unroll
    for (int ks = 0; ks < 5; ++ks) {
        bf16x8 a0 = *(const bf16x8*)&shA1[(ks * 64 + lane) * 8];
        bf16x8 a1 = *(const bf16x8*)&shA1[((5 + ks) * 64 + lane) * 8];
        #pragma unroll
        for (int j = 0; j < 4; ++j) {
            int ntg = wv * 4 + j;
            bf16x8 bw = *(const bf16x8*)&W1f[((ntg * 5 + ks) * 64 + lane) * 8];
            acc1[0][j] = __builtin_amdgcn_mfma_f32_16x16x32_bf16(a0, bw, acc1[0][j], 0, 0, 0);
            acc1[1][j] = __builtin_amdgcn_mfma_f32_16x16x32_bf16(a1, bw, acc1[1][j], 0, 0, 0);
        }
    }
    #pragma unroll
    for (int j = 0; j < 4; ++j) {
        int n = (wv * 4 + j) * 16 + col;
        float bj = mb1[n];
        int ks2 = n >> 5, qd2 = (n >> 3) & 3, off2 = n & 7;
        #pragma unroll
        for (int mt = 0; mt < 2; ++mt)
            #pragma unroll
            for (int i = 0; i < 4; ++i) {
                float z = fmaxf(acc1[mt][j][i] + bj, 0.f);
                shA2[((mt * 8 + ks2) * 64 + qd2 * 16 + quad * 4 + i) * 8 + off2] = f2bf(z);
            }
    }
    __syncthreads();

    f32x4 acc2[2][2];
    #pragma unroll
    for (int mt = 0; mt < 2; ++mt)
        #pragma unroll
        for (int jj = 0; jj < 2; ++jj) acc2[mt][jj] = (f32x4){0.f, 0.f, 0.f, 0.f};
    #pragma unroll
    for (int ks = 0; ks < 8; ++ks) {
        bf16x8 a0 = *(const bf16x8*)&shA2[(ks * 64 + lane) * 8];
        bf16x8 a1 = *(const bf16x8*)&shA2[((8 + ks) * 64 + lane) * 8];
        #pragma unroll
        for (int jj = 0; jj < 2; ++jj) {
            int ntg = wv * 2 + jj;
            bf16x8 bw = *(const bf16x8*)&W2f[((ntg * 8 + ks) * 64 + lane) * 8];
            acc2[0][jj] = __builtin_amdgcn_mfma_f32_16x16x32_bf16(a0, bw, acc2[0][jj], 0, 0, 0);
            acc2[1][jj] = __builtin_amdgcn_mfma_f32_16x16x32_bf16(a1, bw, acc2[1][jj], 0, 0, 0);
        }
    }
    #pragma unroll
    for (int mt = 0; mt < 2; ++mt) {
        #pragma unroll
        for (int i = 0; i < 4; ++i) {
            float p = 0.f;
            #pragma unroll
            for (int jj = 0; jj < 2; ++jj) {
                int n = (wv * 2 + jj) * 16 + col;
                float z = fmaxf(acc2[mt][jj][i] + mb2[n], 0.f);
                p += z * mw3[n];
            }
            p += __shfl_xor(p, 1);
            p += __shfl_xor(p, 2);
            p += __shfl_xor(p, 4);
            p += __shfl_xor(p, 8);
            if (col == 0) sh_part[wv][mt * 16 + quad * 4 + i] = p;
        }
    }
    __syncthreads();
    if (t < 32)
        out[b0 + t] = sh_part[0][t] + sh_part[1][t] + sh_part[2][t] + sh_part[3][t] + mb3[0];
}

extern "C" void kernel_launch(void* const* d_in, const int* in_sizes, int n_in,
                              void* d_out, int out_size, void* d_ws, size_t ws_size,
                              hipStream_t stream) {
    const int*   cid = (const int*)d_in[0];
    const int*   cg  = (const int*)d_in[1];
    const int*   cc  = (const int*)d_in[2];
    const int*   hg  = (const int*)d_in[3];
    const int*   hc  = (const int*)d_in[4];
    const float* user_table = (const float*)d_in[5];
    const float* item_table = (const float*)d_in[6];
    const float* cat_table  = (const float*)d_in[7];
    const float* aw1 = (const float*)d_in[8];
    const float* ab1 = (const float*)d_in[9];
    const float* aw2 = (const float*)d_in[10];
    const float* mw1 = (const float*)d_in[12];
    const float* mb1 = (const float*)d_in[13];
    const float* mw2 = (const float*)d_in[14];
    const float* mb2 = (const float*)d_in[15];
    const float* mw3 = (const float*)d_in[16];
    const float* mb3 = (const float*)d_in[17];
    float* out = (float*)d_out;

    const int B = in_sizes[0];                    // 16384
    const int itemN = in_sizes[6];                // NI*32
    const int catN  = in_sizes[7];                // NC*32
    float* ws = (float*)d_ws;
    unsigned short* W13fb = (unsigned short*)ws;
    unsigned short* Bmfb = (unsigned short*)(ws + 5120);
    unsigned short* W4fb = (unsigned short*)(ws + 7680);
    unsigned short* W1f  = (unsigned short*)(ws + 10240);
    unsigned short* W2f  = (unsigned short*)(ws + 30720);
    unsigned short* itemb = (unsigned short*)(ws + 47104);
    unsigned short* catb  = itemb + itemN;
    float* combined = ws + 47104 + (itemN + catN + 1) / 2;

    int n8 = (itemN + 7) / 8;
    int prep_grid = (n8 + 255) / 256;
    if (prep_grid < 160) prep_grid = 160;
    prep_kernel<<<prep_grid, 256, 0, stream>>>(aw1, mw1, mw2, item_table, cat_table,
                                               itemN, catN, W13fb, Bmfb, W4fb, W1f, W2f,
                                               itemb, catb);
    attn_kernel<<<B / 4, 256, 0, stream>>>(cid, cg, cc, hg, hc,
                                           user_table, item_table, cat_table,
                                           ab1, aw2, W13fb, Bmfb, W4fb, itemb, catb, combined);
    mlp_kernel<<<B / 32, 256, 0, stream>>>(combined, W1f, W2f,
                                           mb1, mb2, mw3, mb3, out);
}

// Round 2
// 250.160 us; speedup vs baseline: 1.3669x; 1.3669x over previous
//
#include <hip/hip_runtime.h>
#include <hip/hip_bf16.h>
#include <math.h>

#define LHIST 50

typedef __attribute__((ext_vector_type(8))) short bf16x8;
typedef __attribute__((ext_vector_type(4))) float f32x4;

__device__ __forceinline__ unsigned short f2bf(float f) {
    union { float f; unsigned u; } v; v.f = f;
    unsigned r = v.u + 0x7fff + ((v.u >> 16) & 1);   // RNE
    return (unsigned short)(r >> 16);
}
__device__ __forceinline__ float bf2f(unsigned short h) {
    union { unsigned u; float f; } v; v.u = ((unsigned)h) << 16;
    return v.f;
}
__device__ __forceinline__ unsigned pk2(float lo, float hi) {   // v_cvt_pk_bf16_f32
    __hip_bfloat162 h = __float22bfloat162_rn(make_float2(lo, hi));
    return *(unsigned*)&h;
}

// ws float offsets:
//  W13fb  frag bf16 [nt5][ks2][lane][8]   @ 0         (2560 f)   (W1+W3)
//  Bmfb   frag bf16 [nt5][ks2][lane][8]   @ 5120      (2560 f)   (W2-W3)
//  W4fb   frag bf16 [nt5][ks2][lane][8]   @ 7680      (2560 f)   (W4)
//  W1f    frag bf16 [nt16][ks5][lane][8]  @ 10240     (20480 f)
//  W2f    frag bf16 [nt8][ks8][lane][8]   @ 30720     (16384 f)
//  itemb  bf16 [NI*32]                    @ 47104     (NI*16 f)
//  catb   bf16 [NC*32]                    @ 47104+NI*16
//  combined [B][160] fp32                 after catb

__global__ void prep_kernel(const float* __restrict__ aw1,
                            const float* __restrict__ mw1,
                            const float* __restrict__ mw2,
                            const float* __restrict__ item_table,
                            const float* __restrict__ cat_table,
                            int itemN, int catN,
                            unsigned short* __restrict__ W13fb,
                            unsigned short* __restrict__ Bmfb,
                            unsigned short* __restrict__ W4fb,
                            unsigned short* __restrict__ W1f,
                            unsigned short* __restrict__ W2f,
                            unsigned short* __restrict__ itemb,
                            unsigned short* __restrict__ catb) {
    int i = blockIdx.x * 256 + threadIdx.x;
    int i8 = i * 8;
    if (i8 + 7 < itemN) {
        float4 a = *(const float4*)&item_table[i8];
        float4 b = *(const float4*)&item_table[i8 + 4];
        uint4 r;
        r.x = pk2(a.x, a.y); r.y = pk2(a.z, a.w);
        r.z = pk2(b.x, b.y); r.w = pk2(b.z, b.w);
        *(uint4*)&itemb[i8] = r;
    }
    if (i8 + 7 < catN) {
        float4 a = *(const float4*)&cat_table[i8];
        float4 b = *(const float4*)&cat_table[i8 + 4];
        uint4 r;
        r.x = pk2(a.x, a.y); r.y = pk2(a.z, a.w);
        r.z = pk2(b.x, b.y); r.w = pk2(b.z, b.w);
        *(uint4*)&catb[i8] = r;
    }
    if (i < 5120) {
        int kk = i / 80, n = i - kk * 80;
        int nt = n >> 4, colw = n & 15, ks = kk >> 5, r = kk & 31, qd = r >> 3, off = r & 7;
        int d = ((nt * 2 + ks) * 64 + qd * 16 + colw) * 8 + off;
        Bmfb[d]  = f2bf(aw1[(64 + kk) * 80 + n] - aw1[(128 + kk) * 80 + n]);   // W2-W3
        W4fb[d]  = f2bf(aw1[(192 + kk) * 80 + n]);                              // W4
        W13fb[d] = f2bf(aw1[kk * 80 + n] + aw1[(128 + kk) * 80 + n]);           // W1+W3
    }
    if (i < 40960) {
        int kk = i >> 8, n = i & 255;
        int nt = n >> 4, colw = n & 15, ks = kk >> 5, r = kk & 31, qd = r >> 3, off = r & 7;
        W1f[((nt * 5 + ks) * 64 + qd * 16 + colw) * 8 + off] = f2bf(mw1[i]);
    }
    if (i < 32768) {
        int kk = i >> 7, n = i & 127;
        int nt = n >> 4, colw = n & 15, ks = kk >> 5, r = kk & 31, qd = r >> 3, off = r & 7;
        W2f[((nt * 8 + ks) * 64 + qd * 16 + colw) * 8 + off] = f2bf(mw2[i]);
    }
}

// ---------- attention: 1 wave = 1 batch, barrier-free, spill-free ----------
// score[l][j] = relu( q.(W1+W3)[j] + h[l].(W2-W3)[:,j] + (h[l]*q).W4[:,j] + ab1[j] ) . aw2
// mi-outer / jt-inner: hq frags are transient (8 VGPR), A-frags are L1-hot reloads.
__global__ void __launch_bounds__(256, 3) attn_kernel(
    const int* __restrict__ cid, const int* __restrict__ cg,
    const int* __restrict__ cc,  const int* __restrict__ hg,
    const int* __restrict__ hc,
    const float* __restrict__ user_table, const float* __restrict__ item_table,
    const float* __restrict__ cat_table,
    const float* __restrict__ ab1, const float* __restrict__ aw2,
    const unsigned short* __restrict__ W13fb, const unsigned short* __restrict__ Bmfb,
    const unsigned short* __restrict__ W4fb,
    const unsigned short* __restrict__ itemb, const unsigned short* __restrict__ catb,
    float* __restrict__ combined)
{
    __shared__ float red[4][1056];   // per-wave private att transpose scratch (16.9 KB)

    const int t = threadIdx.x;
    const int wv = t >> 6;
    const int lane = t & 63;
    const int quad = lane >> 4;
    const int col = lane & 15;
    const int b = blockIdx.x * 4 + wv;

    const int cgb = cg[b], ccb = cc[b];

    // ---- history indices (freed after gathers), bad lanes packed in one mask ----
    int ig[4], icx[4];
    unsigned badmask = 0;
    #pragma unroll
    for (int mi = 0; mi < 4; ++mi) {
        int l = mi * 16 + col;
        int lc = (l < LHIST) ? l : 0;
        ig[mi]  = hg[b * LHIST + lc];
        icx[mi] = hc[b * LHIST + lc];
        if (l >= LHIST || ig[mi] == 0) badmask |= (1u << mi);
    }

    // ---- q fp32 chunks for this lane's d-range (d = quad*8 .. +7), independent loads ----
    const float4 qia = *(const float4*)&item_table[(size_t)cgb * 32 + quad * 8];
    const float4 qib = *(const float4*)&item_table[(size_t)cgb * 32 + quad * 8 + 4];
    const float4 qca = *(const float4*)&cat_table[(size_t)ccb * 32 + quad * 8];
    const float4 qcb = *(const float4*)&cat_table[(size_t)ccb * 32 + quad * 8 + 4];

    // ---- h gathers (32 VGPR, live through score + att phases) ----
    uint4 vi[4], vc[4];
    #pragma unroll
    for (int mi = 0; mi < 4; ++mi) {
        vi[mi] = *(const uint4*)&itemb[(size_t)ig[mi] * 32 + quad * 8];
        vc[mi] = *(const uint4*)&catb[(size_t)icx[mi] * 32 + quad * 8];
    }

    // ---- bias accumulators per j-tile via MFMA (overlaps gather latency) ----
    // broadcast-q B-frags (col-independent): B[k=quad*8+off][*] = q[k]
    f32x4 accb[5];
    {
        uint4 u, v;
        u.x = pk2(qia.x, qia.y); u.y = pk2(qia.z, qia.w);
        u.z = pk2(qib.x, qib.y); u.w = pk2(qib.z, qib.w);
        v.x = pk2(qca.x, qca.y); v.y = pk2(qca.z, qca.w);
        v.z = pk2(qcb.x, qcb.y); v.w = pk2(qcb.z, qcb.w);
        bf16x8 qbi = *(bf16x8*)&u;
        bf16x8 qbc = *(bf16x8*)&v;
        #pragma unroll
        for (int jt = 0; jt < 5; ++jt) {
            bf16x8 w0 = *(const bf16x8*)&W13fb[((jt * 2 + 0) * 64 + lane) * 8];
            bf16x8 w1 = *(const bf16x8*)&W13fb[((jt * 2 + 1) * 64 + lane) * 8];
            f32x4 a = (f32x4){0.f, 0.f, 0.f, 0.f};
            a = __builtin_amdgcn_mfma_f32_16x16x32_bf16(w0, qbi, a, 0, 0, 0);
            a = __builtin_amdgcn_mfma_f32_16x16x32_bf16(w1, qbc, a, 0, 0, 0);
            float4 b4 = *(const float4*)&ab1[jt * 16 + quad * 4];
            a[0] += b4.x; a[1] += b4.y; a[2] += b4.z; a[3] += b4.w;
            accb[jt] = a;
        }
    }

    // ---- score: mi-outer (hq transient), jt-inner (A-frags L1-hot) ----
    float px[4];
    #pragma unroll
    for (int mi = 0; mi < 4; ++mi) {
        // hq = h * q for this mi only (fp32 q, bf16 repack) — 8 transient VGPRs
        bf16x8 hqi, hqc;
        {
            union { uint4 u; unsigned short s[8]; } h;
            h.u = vi[mi];
            uint4 r;
            r.x = pk2(bf2f(h.s[0]) * qia.x, bf2f(h.s[1]) * qia.y);
            r.y = pk2(bf2f(h.s[2]) * qia.z, bf2f(h.s[3]) * qia.w);
            r.z = pk2(bf2f(h.s[4]) * qib.x, bf2f(h.s[5]) * qib.y);
            r.w = pk2(bf2f(h.s[6]) * qib.z, bf2f(h.s[7]) * qib.w);
            hqi = *(bf16x8*)&r;
            h.u = vc[mi];
            uint4 rc;
            rc.x = pk2(bf2f(h.s[0]) * qca.x, bf2f(h.s[1]) * qca.y);
            rc.y = pk2(bf2f(h.s[2]) * qca.z, bf2f(h.s[3]) * qca.w);
            rc.z = pk2(bf2f(h.s[4]) * qcb.x, bf2f(h.s[5]) * qcb.y);
            rc.w = pk2(bf2f(h.s[6]) * qcb.z, bf2f(h.s[7]) * qcb.w);
            hqc = *(bf16x8*)&rc;
        }
        float p = 0.f;
        #pragma unroll
        for (int jt = 0; jt < 5; ++jt) {
            bf16x8 a23_0 = *(const bf16x8*)&Bmfb[((jt * 2 + 0) * 64 + lane) * 8];
            bf16x8 a23_1 = *(const bf16x8*)&Bmfb[((jt * 2 + 1) * 64 + lane) * 8];
            bf16x8 a4_0  = *(const bf16x8*)&W4fb[((jt * 2 + 0) * 64 + lane) * 8];
            bf16x8 a4_1  = *(const bf16x8*)&W4fb[((jt * 2 + 1) * 64 + lane) * 8];
            float4 a2 = *(const float4*)&aw2[jt * 16 + quad * 4];
            f32x4 acc = accb[jt];
            acc = __builtin_amdgcn_mfma_f32_16x16x32_bf16(a23_0, *(bf16x8*)&vi[mi], acc, 0, 0, 0);
            acc = __builtin_amdgcn_mfma_f32_16x16x32_bf16(a23_1, *(bf16x8*)&vc[mi], acc, 0, 0, 0);
            acc = __builtin_amdgcn_mfma_f32_16x16x32_bf16(a4_0, hqi, acc, 0, 0, 0);
            acc = __builtin_amdgcn_mfma_f32_16x16x32_bf16(a4_1, hqc, acc, 0, 0, 0);
            p += fmaxf(acc[0], 0.f) * a2.x
               + fmaxf(acc[1], 0.f) * a2.y
               + fmaxf(acc[2], 0.f) * a2.z
               + fmaxf(acc[3], 0.f) * a2.w;
        }
        // reduce over quads (j coverage): all lanes get full score[l=mi*16+col]
        p += __shfl_xor(p, 16);
        p += __shfl_xor(p, 32);
        px[mi] = p;
    }

    // ---- wave-local softmax over l ----
    float sc[4];
    #pragma unroll
    for (int mi = 0; mi < 4; ++mi) sc[mi] = (badmask & (1u << mi)) ? -1e9f : px[mi];
    float m = fmaxf(fmaxf(sc[0], sc[1]), fmaxf(sc[2], sc[3]));
    #pragma unroll
    for (int off = 8; off >= 1; off >>= 1) m = fmaxf(m, __shfl_xor(m, off));
    float e[4];
    float ssum = 0.f;
    #pragma unroll
    for (int mi = 0; mi < 4; ++mi) {
        int l = mi * 16 + col;
        e[mi] = (l < LHIST) ? __expf(sc[mi] - m) : 0.f;
        ssum += e[mi];
    }
    #pragma unroll
    for (int off = 8; off >= 1; off >>= 1) ssum += __shfl_xor(ssum, off);
    float inv = 1.f / ssum;

    // ---- att partials: this lane's l's weighted into d = quad*8+j ----
    float ati[8], atc[8];
    #pragma unroll
    for (int j = 0; j < 8; ++j) { ati[j] = 0.f; atc[j] = 0.f; }
    #pragma unroll
    for (int mi = 0; mi < 4; ++mi) {
        float w = e[mi] * inv;
        union { uint4 u; unsigned short s[8]; } hi_, hc_;
        hi_.u = vi[mi]; hc_.u = vc[mi];
        #pragma unroll
        for (int j = 0; j < 8; ++j) {
            ati[j] += w * bf2f(hi_.s[j]);
            atc[j] += w * bf2f(hc_.s[j]);
        }
    }

    // ---- wave-private LDS transpose reduce over the 16 col-lanes (no barrier) ----
    float* myrow = &red[wv][col * 66];
    #pragma unroll
    for (int j2 = 0; j2 < 4; ++j2) {
        *(float2*)&myrow[quad * 8 + 2 * j2]      = make_float2(ati[2 * j2], ati[2 * j2 + 1]);
        *(float2*)&myrow[33 + quad * 8 + 2 * j2] = make_float2(atc[2 * j2], atc[2 * j2 + 1]);
    }
    int colIdx = (lane < 32) ? lane : 33 + (lane - 32);
    float s = 0.f;
    #pragma unroll
    for (int c = 0; c < 16; ++c) s += red[wv][c * 66 + colIdx];

    // ---- write combined [user | cand_item | cand_cat | att] ----
    float* crow = combined + (size_t)b * 160;
    const int cidb = cid[b];
    crow[lane] = (lane < 32) ? user_table[(size_t)cidb * 32 + lane]
                             : item_table[(size_t)cgb * 32 + (lane - 32)];
    if (lane < 32) crow[64 + lane] = cat_table[(size_t)ccb * 32 + lane];
    crow[96 + lane] = s;
}

// ---------- MLP: MFMA, 32 batch rows per 256-thread block (unchanged) ----------
__global__ void __launch_bounds__(256, 4) mlp_kernel(
    const float* __restrict__ combined,
    const unsigned short* __restrict__ W1f, const unsigned short* __restrict__ W2f,
    const float* __restrict__ mb1, const float* __restrict__ mb2,
    const float* __restrict__ mw3, const float* __restrict__ mb3,
    float* __restrict__ out)
{
    __shared__ __align__(16) unsigned short shA1[5120];   // [mt2][ks5][lane][8]
    __shared__ __align__(16) unsigned short shA2[8192];   // [mt2][ks8][lane][8]
    __shared__ float sh_part[4][32];

    const int t = threadIdx.x;
    const int b0 = blockIdx.x * 32;
    const int wv = t >> 6;
    const int lane = t & 63;
    const int quad = lane >> 4;
    const int col = lane & 15;

    for (int i = t; i < 1280; i += 256) {
        int m = i / 40;
        int s = i - m * 40;
        int k0 = s * 4;
        float4 v = *(const float4*)&combined[(size_t)(b0 + m) * 160 + k0];
        int mt = m >> 4, colm = m & 15;
        int ks = k0 >> 5, qd = (k0 >> 3) & 3, off = k0 & 7;
        ushort4 r; r.x = f2bf(v.x); r.y = f2bf(v.y); r.z = f2bf(v.z); r.w = f2bf(v.w);
        *(ushort4*)&shA1[((mt * 5 + ks) * 64 + qd * 16 + colm) * 8 + off] = r;
    }
    __syncthreads();

    f32x4 acc1[2][4];
    #pragma unroll
    for (int mt = 0; mt < 2; ++mt)
        #pragma unroll
        for (int j = 0; j < 4; ++j) acc1[mt][j] = (f32x4){0.f, 0.f, 0.f, 0.f};
    #pragma unroll
    for (int ks = 0; ks < 5; ++ks) {
        bf16x8 a0 = *(const bf16x8*)&shA1[(ks * 64 + lane) * 8];
        bf16x8 a1 = *(const bf16x8*)&shA1[((5 + ks) * 64 + lane) * 8];
        #pragma unroll
        for (int j = 0; j < 4; ++j) {
            int ntg = wv * 4 + j;
            bf16x8 bw = *(const bf16x8*)&W1f[((ntg * 5 + ks) * 64 + lane) * 8];
            acc1[0][j] = __builtin_amdgcn_mfma_f32_16x16x32_bf16(a0, bw, acc1[0][j], 0, 0, 0);
            acc1[1][j] = __builtin_amdgcn_mfma_f32_16x16x32_bf16(a1, bw, acc1[1][j], 0, 0, 0);
        }
    }
    #pragma unroll
    for (int j = 0; j < 4; ++j) {
        int n = (wv * 4 + j) * 16 + col;
        float bj = mb1[n];
        int ks2 = n >> 5, qd2 = (n >> 3) & 3, off2 = n & 7;
        #pragma unroll
        for (int mt = 0; mt < 2; ++mt)
            #pragma unroll
            for (int i = 0; i < 4; ++i) {
                float z = fmaxf(acc1[mt][j][i] + bj, 0.f);
                shA2[((mt * 8 + ks2) * 64 + qd2 * 16 + quad * 4 + i) * 8 + off2] = f2bf(z);
            }
    }
    __syncthreads();

    f32x4 acc2[2][2];
    #pragma unroll
    for (int mt = 0; mt < 2; ++mt)
        #pragma unroll
        for (int jj = 0; jj < 2; ++jj) acc2[mt][jj] = (f32x4){0.f, 0.f, 0.f, 0.f};
    #pragma unroll
    for (int ks = 0; ks < 8; ++ks) {
        bf16x8 a0 = *(const bf16x8*)&shA2[(ks * 64 + lane) * 8];
        bf16x8 a1 = *(const bf16x8*)&shA2[((8 + ks) * 64 + lane) * 8];
        #pragma unroll
        for (int jj = 0; jj < 2; ++jj) {
            int ntg = wv * 2 + jj;
            bf16x8 bw = *(const bf16x8*)&W2f[((ntg * 8 + ks) * 64 + lane) * 8];
            acc2[0][jj] = __builtin_amdgcn_mfma_f32_16x16x32_bf16(a0, bw, acc2[0][jj], 0, 0, 0);
            acc2[1][jj] = __builtin_amdgcn_mfma_f32_16x16x32_bf16(a1, bw, acc2[1][jj], 0, 0, 0);
        }
    }
    #pragma unroll
    for (int mt = 0; mt < 2; ++mt) {
        #pragma unroll
        for (int i = 0; i < 4; ++i) {
            float p = 0.f;
            #pragma unroll
            for (int jj = 0; jj < 2; ++jj) {
                int n = (wv * 2 + jj) * 16 + col;
                float z = fmaxf(acc2[mt][jj][i] + mb2[n], 0.f);
                p += z * mw3[n];
            }
            p += __shfl_xor(p, 1);
            p += __shfl_xor(p, 2);
            p += __shfl_xor(p, 4);
            p += __shfl_xor(p, 8);
            if (col == 0) sh_part[wv][mt * 16 + quad * 4 + i] = p;
        }
    }
    __syncthreads();
    if (t < 32)
        out[b0 + t] = sh_part[0][t] + sh_part[1][t] + sh_part[2][t] + sh_part[3][t] + mb3[0];
}

extern "C" void kernel_launch(void* const* d_in, const int* in_sizes, int n_in,
                              void* d_out, int out_size, void* d_ws, size_t ws_size,
                              hipStream_t stream) {
    const int*   cid = (const int*)d_in[0];
    const int*   cg  = (const int*)d_in[1];
    const int*   cc  = (const int*)d_in[2];
    const int*   hg  = (const int*)d_in[3];
    const int*   hc  = (const int*)d_in[4];
    const float* user_table = (const float*)d_in[5];
    const float* item_table = (const float*)d_in[6];
    const float* cat_table  = (const float*)d_in[7];
    const float* aw1 = (const float*)d_in[8];
    const float* ab1 = (const float*)d_in[9];
    const float* aw2 = (const float*)d_in[10];
    const float* mw1 = (const float*)d_in[12];
    const float* mb1 = (const float*)d_in[13];
    const float* mw2 = (const float*)d_in[14];
    const float* mb2 = (const float*)d_in[15];
    const float* mw3 = (const float*)d_in[16];
    const float* mb3 = (const float*)d_in[17];
    float* out = (float*)d_out;

    const int B = in_sizes[0];                    // 16384
    const int itemN = in_sizes[6];                // NI*32
    const int catN  = in_sizes[7];                // NC*32
    float* ws = (float*)d_ws;
    unsigned short* W13fb = (unsigned short*)ws;
    unsigned short* Bmfb = (unsigned short*)(ws + 5120);
    unsigned short* W4fb = (unsigned short*)(ws + 7680);
    unsigned short* W1f  = (unsigned short*)(ws + 10240);
    unsigned short* W2f  = (unsigned short*)(ws + 30720);
    unsigned short* itemb = (unsigned short*)(ws + 47104);
    unsigned short* catb  = itemb + itemN;
    float* combined = ws + 47104 + (itemN + catN + 1) / 2;

    int n8 = (itemN + 7) / 8;
    int prep_grid = (n8 + 255) / 256;
    if (prep_grid < 160) prep_grid = 160;
    prep_kernel<<<prep_grid, 256, 0, stream>>>(aw1, mw1, mw2, item_table, cat_table,
                                               itemN, catN, W13fb, Bmfb, W4fb, W1f, W2f,
                                               itemb, catb);
    attn_kernel<<<B / 4, 256, 0, stream>>>(cid, cg, cc, hg, hc,
                                           user_table, item_table, cat_table,
                                           ab1, aw2, W13fb, Bmfb, W4fb, itemb, catb, combined);
    mlp_kernel<<<B / 32, 256, 0, stream>>>(combined, W1f, W2f,
                                           mb1, mb2, mw3, mb3, out);
}